// Round 9
// baseline (14054.132 us; speedup 1.0000x reference)
//
#include <hip/hip_runtime.h>

#define R     8192
#define C1    8213
#define C2    8192
#define KROW  8224      // K row stride in BYTES (514 x 16B chunks, zero-padded)
#define TROW  8192      // KT row stride in BYTES (512 x 16B chunks)
#define NKC   514
#define NTC   512
#define NBLK  512       // persistent grid (2 blocks/CU by capacity)
#define TPB   512
#define CPF   8224      // v length in floats

typedef float f32x2 __attribute__((ext_vector_type(2)));

__device__ __forceinline__ void fp8x16_to_f(const int4 w, float f[16]) {
    f32x2 p;
    p = __builtin_amdgcn_cvt_pk_f32_fp8(w.x, false); f[0]  = p.x; f[1]  = p.y;
    p = __builtin_amdgcn_cvt_pk_f32_fp8(w.x, true);  f[2]  = p.x; f[3]  = p.y;
    p = __builtin_amdgcn_cvt_pk_f32_fp8(w.y, false); f[4]  = p.x; f[5]  = p.y;
    p = __builtin_amdgcn_cvt_pk_f32_fp8(w.y, true);  f[6]  = p.x; f[7]  = p.y;
    p = __builtin_amdgcn_cvt_pk_f32_fp8(w.z, false); f[8]  = p.x; f[9]  = p.y;
    p = __builtin_amdgcn_cvt_pk_f32_fp8(w.z, true);  f[10] = p.x; f[11] = p.y;
    p = __builtin_amdgcn_cvt_pk_f32_fp8(w.w, false); f[12] = p.x; f[13] = p.y;
    p = __builtin_amdgcn_cvt_pk_f32_fp8(w.w, true);  f[14] = p.x; f[15] = p.y;
}

__device__ __forceinline__ float fp8_to_f(int byte) {
    f32x2 p = __builtin_amdgcn_cvt_pk_f32_fp8(byte & 0xff, false);
    return p.x;
}

__device__ __forceinline__ float gm_label(float sc, int lab) {
    if (lab == 0) return fmaxf(-0.02f - sc, 0.0f) + fmaxf(sc, 0.0f);
    if (lab == 3) return fmaxf(0.09f + sc, 0.0f);
    return fmaxf(0.05f + sc, 0.0f) + fmaxf(-0.09f - sc, 0.0f); // labels 1|2
}

__device__ __forceinline__ float kval(float gm) {
    // K = exp(-M/REG), M = exp(-GM), REG = -0.2 -> exp(5*exp(-GM)); hw exp
    return __expf(5.0f * __expf(-gm));
}

__device__ __forceinline__ void load_w16(const float4* __restrict__ p4, int ch, float w[16]) {
    float4 q0 = p4[ch * 4], q1 = p4[ch * 4 + 1];
    float4 q2 = p4[ch * 4 + 2], q3 = p4[ch * 4 + 3];
    w[0] = q0.x;  w[1] = q0.y;  w[2]  = q0.z;  w[3]  = q0.w;
    w[4] = q1.x;  w[5] = q1.y;  w[6]  = q1.z;  w[7]  = q1.w;
    w[8] = q2.x;  w[9] = q2.y;  w[10] = q2.z;  w[11] = q2.w;
    w[12] = q3.x; w[13] = q3.y; w[14] = q3.z; w[15] = q3.w;
}

__device__ __forceinline__ float dot16(const float f[16], const float w[16]) {
    float d = 0.0f;
#pragma unroll
    for (int k = 0; k < 16; ++k) d = fmaf(f[k], w[k], d);
    return d;
}

__device__ __forceinline__ float sum16(const float f[16]) {
    float d = 0.0f;
#pragma unroll
    for (int k = 0; k < 16; ++k) d += f[k];
    return d;
}

// ---- build kernels (R5-proven) ----

__global__ __launch_bounds__(256) void build_k1(const float* __restrict__ dist,
                                                const int* __restrict__ lab,
                                                unsigned char* __restrict__ K) {
    int row = blockIdx.y;
    int j0 = (blockIdx.x * 256 + threadIdx.x) * 4;
    if (j0 >= KROW) return;
    size_t ib = (size_t)row * C1;
    float d0 = dist[ib];
    float val[4];
#pragma unroll
    for (int k = 0; k < 4; ++k) {
        int j = j0 + k;
        val[k] = 0.0f;
        if (j < C1) {
            float g = gm_label(dist[ib + j] - d0, lab[ib + j]);
            val[k] = kval(g);
        }
    }
    int p = 0;
    p = __builtin_amdgcn_cvt_pk_fp8_f32(val[0], val[1], p, false);
    p = __builtin_amdgcn_cvt_pk_fp8_f32(val[2], val[3], p, true);
    *reinterpret_cast<int*>(K + (size_t)row * KROW + j0) = p;
}

__global__ __launch_bounds__(256) void diag_k(const float* __restrict__ dist,
                                              float* __restrict__ dcol) {
    int j = blockIdx.x * 256 + threadIdx.x;
    if (j < R) dcol[j] = dist[(size_t)j * C1 + 21 + j];
}

__global__ __launch_bounds__(256) void build_k2(const float* __restrict__ dist,
                                                const float* __restrict__ dcol,
                                                unsigned char* __restrict__ K) {
    int row = blockIdx.y;
    int j0 = (blockIdx.x * 256 + threadIdx.x) * 4;
    if (j0 >= KROW) return;
    size_t ib = (size_t)row * C1 + 21;
    float val[4];
#pragma unroll
    for (int k = 0; k < 4; ++k) {
        int j = j0 + k;
        val[k] = 0.0f;
        if (j < C2) {
            float s = dist[ib + j] - dcol[j];
            float g = (j == row) ? 0.0f : fmaxf(0.09f + s, 0.0f);
            val[k] = kval(g);
        }
    }
    int p = 0;
    p = __builtin_amdgcn_cvt_pk_fp8_f32(val[0], val[1], p, false);
    p = __builtin_amdgcn_cvt_pk_fp8_f32(val[2], val[3], p, true);
    *reinterpret_cast<int*>(K + (size_t)row * KROW + j0) = p;
}

// ---- byte transpose K[8192][KROW] -> KT[8224][TROW] via 64x64 LDS tile ----
__global__ __launch_bounds__(256) void transpose_k(const unsigned char* __restrict__ K,
                                                   unsigned char* __restrict__ KT) {
    __shared__ unsigned char tile[64][64];
    int i0 = blockIdx.x * 64;   // K row block
    int j0 = blockIdx.y * 64;   // K col block
    int t = threadIdx.x;
    int r = t >> 2, cb = (t & 3) << 4;
    if (j0 + cb < KROW) {
        int4 w = *reinterpret_cast<const int4*>(K + (size_t)(i0 + r) * KROW + j0 + cb);
        *reinterpret_cast<int4*>(&tile[r][cb]) = w;
    }
    __syncthreads();
    int jl = t >> 2, ib = (t & 3) << 4;
    if (j0 + jl < KROW) {
        unsigned char tmp[16];
#pragma unroll
        for (int k = 0; k < 16; ++k) tmp[k] = tile[ib + k][jl];
        *reinterpret_cast<int4*>(KT + (size_t)(j0 + jl) * TROW + i0 + ib) =
            *reinterpret_cast<const int4*>(tmp);
    }
}

// ---- barrier: 64 arrival lines, wave-parallel aggregate, 64 epoch lines;
//      RELAXED polls + one acquire fence on exit ----

__global__ void zero_bar(unsigned* __restrict__ bar) {
    int i = threadIdx.x;
    if (i < 128) bar[i << 6] = 0u;
}

__device__ __forceinline__ void gridbar(unsigned* __restrict__ ctr,
                                        unsigned* __restrict__ ep,
                                        int b, unsigned k) {
    __syncthreads();
    if (threadIdx.x == 0)
        __hip_atomic_fetch_add(&ctr[(b & 63) << 6], 1u, __ATOMIC_RELEASE,
                               __HIP_MEMORY_SCOPE_AGENT);
    if (b == 0) {
        if (threadIdx.x < 64) {
            int l = threadIdx.x;
            const unsigned target = k * (unsigned)NBLK;
            for (;;) {
                unsigned s = __hip_atomic_load(&ctr[l << 6], __ATOMIC_RELAXED,
                                               __HIP_MEMORY_SCOPE_AGENT);
#pragma unroll
                for (int off = 32; off; off >>= 1) s += __shfl_down(s, off, 64);
                s = __shfl(s, 0, 64);
                if (s >= target) break;
                __builtin_amdgcn_s_sleep(1);
            }
            __builtin_amdgcn_fence(__ATOMIC_ACQUIRE, "agent");
            __hip_atomic_store(&ep[l << 6], k, __ATOMIC_RELEASE,
                               __HIP_MEMORY_SCOPE_AGENT);
        }
    } else {
        if (threadIdx.x == 0) {
            unsigned* my = &ep[(b & 63) << 6];
            while (__hip_atomic_load(my, __ATOMIC_RELAXED,
                                     __HIP_MEMORY_SCOPE_AGENT) < k)
                __builtin_amdgcn_s_sleep(2);
            __builtin_amdgcn_fence(__ATOMIC_ACQUIRE, "agent");
        }
    }
    __syncthreads();
}

// ---- persistent Sinkhorn: lane owns ONE chunk (w16 loaded once/phase),
//      loops the block's 16 rows with coalesced K loads; butterfly + LDS reduce. ----
__global__ __launch_bounds__(TPB, 4) void sink_k(const unsigned char* __restrict__ K,
                                                 const unsigned char* __restrict__ KT,
                                                 float* __restrict__ u,
                                                 float* __restrict__ v,
                                                 unsigned* __restrict__ ctr,
                                                 unsigned* __restrict__ ep,
                                                 int C, float aval, float bval) {
    __shared__ float lds_p[8][17];
    __shared__ float sp[8];
    const int tx = threadIdx.x, b = blockIdx.x;
    const int lane = tx & 63, wv = tx >> 6;
    const int ch = (wv << 6) | lane;          // this thread's chunk (0..511)
    const int4* Kb = reinterpret_cast<const int4*>(K);
    const int4* KTb = reinterpret_cast<const int4*>(KT);
    const float4* u4 = reinterpret_cast<const float4*>(u);
    const float4* v4 = reinterpret_cast<const float4*>(v);
    const bool isSpec = (b & 15) == 0;
    const int je = 8192 + (b >> 4);
    const int rbase = b * 16;
    unsigned bark = 0;

    for (int t = 0; t < 50; ++t) {
        // ---- column phase: v[j] = bval / (KT[j] . u), j = rbase..rbase+15 ----
        {
            float w[16];
            if (t > 0) load_w16(u4, ch, w);
            float p[16];
            if (t == 0) {
#pragma unroll
                for (int r = 0; r < 16; ++r) {
                    float f[16];
                    fp8x16_to_f(KTb[(size_t)(rbase + r) * NTC + ch], f);
                    p[r] = sum16(f) * aval;
                }
            } else {
#pragma unroll
                for (int r = 0; r < 16; ++r) {
                    float f[16];
                    fp8x16_to_f(KTb[(size_t)(rbase + r) * NTC + ch], f);
                    p[r] = dot16(f, w);
                }
            }
#pragma unroll
            for (int r = 0; r < 16; ++r) {
#pragma unroll
                for (int off = 32; off; off >>= 1) p[r] += __shfl_xor(p[r], off, 64);
            }
            if (lane < 16) lds_p[wv][lane] = p[lane];
            if (isSpec) {
                float f[16];
                fp8x16_to_f(KTb[(size_t)je * NTC + ch], f);
                float de = (t == 0) ? sum16(f) * aval : dot16(f, w);
#pragma unroll
                for (int off = 32; off; off >>= 1) de += __shfl_xor(de, off, 64);
                if (lane == 0) sp[wv] = de;
            }
            __syncthreads();
            if (tx < 16) {
                float s = 0.0f;
#pragma unroll
                for (int q = 0; q < 8; ++q) s += lds_p[q][tx];
                int j = rbase + tx;
                v[j] = (j < C) ? bval / s : 0.0f;
            }
            if (isSpec && tx == 16) {
                float s = sp[0] + sp[1] + sp[2] + sp[3] + sp[4] + sp[5] + sp[6] + sp[7];
                v[je] = (je < C) ? bval / s : 0.0f;
            }
        }
        gridbar(ctr, ep, b, ++bark);
        if (t == 49) break;

        // ---- row phase: u[i] = aval / (K[i] . v), i = rbase..rbase+15 ----
        {
            float w[16];
            load_w16(v4, ch, w);
            float p[16];
#pragma unroll
            for (int r = 0; r < 16; ++r) {
                float f[16];
                fp8x16_to_f(Kb[(size_t)(rbase + r) * NKC + ch], f);
                p[r] = dot16(f, w);
            }
            if (wv == 0 && lane < 2) {          // tail chunks 512, 513
                int cht = 512 + lane;
                float wt[16];
                load_w16(v4, cht, wt);
#pragma unroll
                for (int r = 0; r < 16; ++r) {
                    float f[16];
                    fp8x16_to_f(Kb[(size_t)(rbase + r) * NKC + cht], f);
                    p[r] += dot16(f, wt);
                }
            }
#pragma unroll
            for (int r = 0; r < 16; ++r) {
#pragma unroll
                for (int off = 32; off; off >>= 1) p[r] += __shfl_xor(p[r], off, 64);
            }
            if (lane < 16) lds_p[wv][lane] = p[lane];
            __syncthreads();
            if (tx < 16) {
                float s = 0.0f;
#pragma unroll
                for (int q = 0; q < 8; ++q) s += lds_p[q][tx];
                u[rbase + tx] = aval / s;
            }
        }
        gridbar(ctr, ep, b, ++bark);
    }
}

// ---- loss reductions (R5-proven) ----

__device__ __forceinline__ float2 block_reduce_2(float x, float y, float* sb) {
#pragma unroll
    for (int off = 32; off; off >>= 1) {
        x += __shfl_down(x, off, 64);
        y += __shfl_down(y, off, 64);
    }
    if ((threadIdx.x & 63) == 0) {
        int w = threadIdx.x >> 6;
        sb[w] = x; sb[4 + w] = y;
    }
    __syncthreads();
    float2 r;
    r.x = sb[0] + sb[1] + sb[2] + sb[3];
    r.y = sb[4] + sb[5] + sb[6] + sb[7];
    __syncthreads();
    return r;
}

__global__ __launch_bounds__(256) void loss1_k(const unsigned char* __restrict__ K,
                                               const float* __restrict__ v,
                                               const float* __restrict__ dist,
                                               const int* __restrict__ lab,
                                               float* __restrict__ ratio) {
    __shared__ float sb[8];
    int i = blockIdx.x;
    size_t ib = (size_t)i * C1;
    float d0 = dist[ib];
    const unsigned char* Kr = K + (size_t)i * KROW;
    float num = 0, den = 0;
    for (int j0 = threadIdx.x * 4; j0 < C1; j0 += 1024) {
        int p = *reinterpret_cast<const int*>(Kr + j0);
#pragma unroll
        for (int k = 0; k < 4; ++k) {
            int j = j0 + k;
            int jc = (j < C1) ? j : (C1 - 1);
            float kv = fp8_to_f(p >> (k * 8)) * v[jc];   // K pad = 0 -> kv = 0 beyond C1
            float g = gm_label(dist[ib + jc] - d0, lab[ib + jc]);
            den += kv;
            num = fmaf(g, kv, num);
        }
    }
    float2 r = block_reduce_2(num, den, sb);
    if (threadIdx.x == 0) ratio[i] = r.x / r.y;
}

__global__ __launch_bounds__(256) void loss2_k(const unsigned char* __restrict__ K,
                                               const float* __restrict__ v,
                                               const float* __restrict__ dist,
                                               const float* __restrict__ dcol,
                                               float* __restrict__ ratio) {
    __shared__ float sb[8];
    int i = blockIdx.x;
    const unsigned char* Kr = K + (size_t)i * KROW;
    const float* Dr = dist + (size_t)i * C1 + 21;
    float num = 0, den = 0;
    for (int j0 = threadIdx.x * 4; j0 < C2; j0 += 1024) {
        int p = *reinterpret_cast<const int*>(Kr + j0);
#pragma unroll
        for (int k = 0; k < 4; ++k) {
            int j = j0 + k;
            if (j == i) continue;
            float kv = fp8_to_f(p >> (k * 8)) * v[j];
            float h = fmaxf(0.09f + Dr[j] - dcol[j], 0.0f);
            den += kv;
            num = fmaf(h, kv, num);
        }
    }
    float2 r = block_reduce_2(num, den, sb);
    if (threadIdx.x == 0) ratio[i] = r.x / r.y;
}

__global__ __launch_bounds__(256) void final_k(const float* __restrict__ r1,
                                               const float* __restrict__ r2,
                                               float* __restrict__ out) {
    __shared__ float sb[8];
    float s1 = 0, s2 = 0;
    for (int i = threadIdx.x; i < R; i += 256) { s1 += r1[i]; s2 += r2[i]; }
    float2 t = block_reduce_2(s1, s2, sb);
    if (threadIdx.x == 0)
        out[0] = t.x / ((float)R * (float)C1) + t.y / ((float)R * (float)C2);
}

extern "C" void kernel_launch(void* const* d_in, const int* in_sizes, int n_in,
                              void* d_out, int out_size, void* d_ws, size_t ws_size,
                              hipStream_t stream) {
    const float* dist = (const float*)d_in[0];
    const int* lab = (const int*)d_in[1];
    float* out = (float*)d_out;
    char* ws = (char*)d_ws;

    size_t need = (size_t)R * KROW                       // K (fp8)
                + (size_t)KROW * TROW                    // KT (fp8)
                + (size_t)CPF * sizeof(float)            // v
                + 4 * (size_t)R * sizeof(float)          // u, dcol, rat1, rat2
                + 128 * 256;                             // barrier lines
    if (ws_size < need) return;

    size_t off = 0;
    unsigned char* K = (unsigned char*)(ws + off);  off += (size_t)R * KROW;
    unsigned char* KT = (unsigned char*)(ws + off); off += (size_t)KROW * TROW;
    float* v = (float*)(ws + off);     off += (size_t)CPF * sizeof(float);
    float* u = (float*)(ws + off);     off += (size_t)R * sizeof(float);
    float* dcol = (float*)(ws + off);  off += (size_t)R * sizeof(float);
    float* rat1 = (float*)(ws + off);  off += (size_t)R * sizeof(float);
    float* rat2 = (float*)(ws + off);  off += (size_t)R * sizeof(float);
    unsigned* bar = (unsigned*)(ws + off); off += 128 * 256;
    unsigned* ctr = bar;              // 64 lines
    unsigned* epb = bar + 64 * 64;    // 64 lines

    float aval = 1.0f / (float)R;
    int gb = (KROW / 4 + 255) / 256;   // 9 blocks per row

    // ---- phase 1 ----
    build_k1<<<dim3(gb, R), 256, 0, stream>>>(dist, lab, K);
    transpose_k<<<dim3(R / 64, (KROW + 63) / 64), 256, 0, stream>>>(K, KT);
    zero_bar<<<dim3(1), 128, 0, stream>>>(bar);
    sink_k<<<dim3(NBLK), TPB, 0, stream>>>(K, KT, u, v, ctr, epb, C1, aval,
                                           1.0f / (float)C1);
    loss1_k<<<dim3(R), 256, 0, stream>>>(K, v, dist, lab, rat1);

    // ---- phase 2 (reuses K and KT buffers) ----
    diag_k<<<dim3(R / 256), 256, 0, stream>>>(dist, dcol);
    build_k2<<<dim3(gb, R), 256, 0, stream>>>(dist, dcol, K);
    transpose_k<<<dim3(R / 64, (KROW + 63) / 64), 256, 0, stream>>>(K, KT);
    zero_bar<<<dim3(1), 128, 0, stream>>>(bar);
    sink_k<<<dim3(NBLK), TPB, 0, stream>>>(K, KT, u, v, ctr, epb, C2, aval,
                                           1.0f / (float)C2);
    loss2_k<<<dim3(R), 256, 0, stream>>>(K, v, dist, dcol, rat2);

    final_k<<<dim3(1), 256, 0, stream>>>(rat1, rat2, out);
}